// Round 4
// baseline (117.054 us; speedup 1.0000x reference)
//
#include <hip/hip_runtime.h>
#include <math.h>

#define D 512
#define R_BLK 128     // rows owned per block in pass 1
#define HALO 8        // supports window half-width k <= 8 (bench uses k=4)
#define NB_P 2048     // partial-bag blocks

// ---- K1: fused row-dot + windowed-mean scores + block softmax partials ----
// Block: 512 threads (8 waves). Computes dots for 144 rows (128 owned + halo)
// into LDS, then scores for its 128 rows, then per-block (max, expsum).
__global__ __launch_bounds__(512) void k_scores(
    const float* __restrict__ f, const float* __restrict__ w,
    const float* __restrict__ bptr, const int* __restrict__ kptr,
    float* __restrict__ scores, float* __restrict__ pmax,
    float* __restrict__ psum, int n)
{
    __shared__ float dots[R_BLK + 2 * HALO];   // 144
    __shared__ float sm[8];
    __shared__ float bmax;

    int lane = threadIdx.x & 63;
    int wid  = threadIdx.x >> 6;               // 0..7
    int g0   = blockIdx.x * R_BLK - HALO;      // global row of dots[0]

    const float4* wr = (const float4*)w;
    float4 b0 = wr[lane], b1 = wr[lane + 64];

    // 144 rows = 72 pairs; wave `wid` handles pairs wid, wid+8, ... (9 iters)
    for (int p = wid; p < (R_BLK + 2 * HALO) / 2; p += 8) {
        int r0 = g0 + 2 * p;
        int r1 = r0 + 1;
        bool v0 = (r0 >= 0) && (r0 < n);
        bool v1 = (r1 >= 0) && (r1 < n);
        const float4* fr0 = (const float4*)(f + (size_t)(v0 ? r0 : 0) * D);
        const float4* fr1 = (const float4*)(f + (size_t)(v1 ? r1 : 0) * D);
        float4 a0 = fr0[lane], a1 = fr0[lane + 64];
        float4 c0 = fr1[lane], c1 = fr1[lane + 64];
        float s0 = a0.x*b0.x + a0.y*b0.y + a0.z*b0.z + a0.w*b0.w
                 + a1.x*b1.x + a1.y*b1.y + a1.z*b1.z + a1.w*b1.w;
        float s1 = c0.x*b0.x + c0.y*b0.y + c0.z*b0.z + c0.w*b0.w
                 + c1.x*b1.x + c1.y*b1.y + c1.z*b1.z + c1.w*b1.w;
        #pragma unroll
        for (int off = 32; off; off >>= 1) {
            s0 += __shfl_down(s0, off);
            s1 += __shfl_down(s1, off);
        }
        if (lane == 0) {
            dots[2 * p]     = v0 ? s0 : 0.f;
            dots[2 * p + 1] = v1 ? s1 : 0.f;
        }
    }
    __syncthreads();

    int k = *kptr;
    float val = -INFINITY;
    int i = blockIdx.x * R_BLK + threadIdx.x;   // threads 0..127 own rows
    if (threadIdx.x < R_BLK && i < n) {
        int lo = max(i - k, 0), hi = min(i + k, n - 1);
        float s = 0.f;
        for (int g = lo; g <= hi; ++g) s += dots[g - g0];
        val = s / (float)(hi - lo + 1) + bptr[0];
        scores[i] = val;
    }

    // block softmax partials over all 512 threads (inactive hold -inf / 0)
    float m = val;
    #pragma unroll
    for (int off = 32; off; off >>= 1) m = fmaxf(m, __shfl_down(m, off));
    if (lane == 0) sm[wid] = m;
    __syncthreads();
    if (threadIdx.x == 0) {
        float mm = sm[0];
        #pragma unroll
        for (int q = 1; q < 8; ++q) mm = fmaxf(mm, sm[q]);
        bmax = mm;
    }
    __syncthreads();
    float mb = bmax;
    float e = (val == -INFINITY) ? 0.f : __expf(val - mb);
    #pragma unroll
    for (int off = 32; off; off >>= 1) e += __shfl_down(e, off);
    __syncthreads();               // sm reuse guard
    if (lane == 0) sm[wid] = e;
    __syncthreads();
    if (threadIdx.x == 0) {
        float ss = 0.f;
        #pragma unroll
        for (int q = 0; q < 8; ++q) ss += sm[q];
        pmax[blockIdx.x] = mb;
        psum[blockIdx.x] = ss;
    }
}

// ---- K2: inline-combine partials, then w[j] and u[j] ------------------------
// u[j] = inv * sum_{i in win(j)} exp(scores[i]-gmax)/cnt(i)
__global__ __launch_bounds__(256) void k_wu(
    const float* __restrict__ scores, const float* __restrict__ pmax,
    const float* __restrict__ psum, int nb1,
    const int* __restrict__ kptr, float* __restrict__ w_out,
    float* __restrict__ u, int n)
{
    __shared__ float sm[4];
    __shared__ float gshared[2];
    int lane = threadIdx.x & 63, wid = threadIdx.x >> 6;

    // global max (each block redundantly reduces nb1 entries — L2-hit)
    float m = -INFINITY;
    for (int idx = threadIdx.x; idx < nb1; idx += 256) m = fmaxf(m, pmax[idx]);
    #pragma unroll
    for (int off = 32; off; off >>= 1) m = fmaxf(m, __shfl_down(m, off));
    if (lane == 0) sm[wid] = m;
    __syncthreads();
    if (threadIdx.x == 0)
        gshared[0] = fmaxf(fmaxf(sm[0], sm[1]), fmaxf(sm[2], sm[3]));
    __syncthreads();
    float gmax = gshared[0];

    // global sum
    float s = 0.f;
    for (int idx = threadIdx.x; idx < nb1; idx += 256)
        s += psum[idx] * __expf(pmax[idx] - gmax);
    #pragma unroll
    for (int off = 32; off; off >>= 1) s += __shfl_down(s, off);
    __syncthreads();               // sm reuse guard
    if (lane == 0) sm[wid] = s;
    __syncthreads();
    if (threadIdx.x == 0)
        gshared[1] = 1.f / (sm[0] + sm[1] + sm[2] + sm[3]);
    __syncthreads();
    float inv = gshared[1];

    int j = blockIdx.x * 256 + threadIdx.x;
    if (j >= n) return;
    int k = *kptr;
    float ej = __expf(scores[j] - gmax);
    w_out[j] = ej * inv;
    int lo = max(j - k, 0), hi = min(j + k, n - 1);
    float acc = 0.f;
    for (int i = lo; i <= hi; ++i) {
        int li = max(i - k, 0), hh = min(i + k, n - 1);
        float e = __expf(scores[i] - gmax);
        acc += e * __builtin_amdgcn_rcpf((float)(hh - li + 1));
    }
    u[j] = acc * inv;
}

// ---- K3: partial bag per block (unroll 4, 4 accumulators) -------------------
__global__ __launch_bounds__(128) void k_pbag(
    const float* __restrict__ f, const float* __restrict__ u,
    float* __restrict__ partial, int n, int chunk)
{
    int t = threadIdx.x;                     // 128 threads x float4 = 512 cols
    int j0 = blockIdx.x * chunk;
    int j1 = min(j0 + chunk, n);
    float4 acc0 = make_float4(0.f,0.f,0.f,0.f);
    float4 acc1 = make_float4(0.f,0.f,0.f,0.f);
    float4 acc2 = make_float4(0.f,0.f,0.f,0.f);
    float4 acc3 = make_float4(0.f,0.f,0.f,0.f);
    int j = j0;
    for (; j + 4 <= j1; j += 4) {
        float u0 = u[j], u1 = u[j+1], u2 = u[j+2], u3 = u[j+3];
        float4 v0 = ((const float4*)(f + (size_t)(j  ) * D))[t];
        float4 v1 = ((const float4*)(f + (size_t)(j+1) * D))[t];
        float4 v2 = ((const float4*)(f + (size_t)(j+2) * D))[t];
        float4 v3 = ((const float4*)(f + (size_t)(j+3) * D))[t];
        acc0.x += u0*v0.x; acc0.y += u0*v0.y; acc0.z += u0*v0.z; acc0.w += u0*v0.w;
        acc1.x += u1*v1.x; acc1.y += u1*v1.y; acc1.z += u1*v1.z; acc1.w += u1*v1.w;
        acc2.x += u2*v2.x; acc2.y += u2*v2.y; acc2.z += u2*v2.z; acc2.w += u2*v2.w;
        acc3.x += u3*v3.x; acc3.y += u3*v3.y; acc3.z += u3*v3.z; acc3.w += u3*v3.w;
    }
    for (; j < j1; ++j) {
        float uj = u[j];
        float4 v = ((const float4*)(f + (size_t)j * D))[t];
        acc0.x += uj*v.x; acc0.y += uj*v.y; acc0.z += uj*v.z; acc0.w += uj*v.w;
    }
    float4 a;
    a.x = (acc0.x + acc1.x) + (acc2.x + acc3.x);
    a.y = (acc0.y + acc1.y) + (acc2.y + acc3.y);
    a.z = (acc0.z + acc1.z) + (acc2.z + acc3.z);
    a.w = (acc0.w + acc1.w) + (acc2.w + acc3.w);
    ((float4*)(partial + (size_t)blockIdx.x * D))[t] = a;   // zeros if empty range
}

// ---- K4: reduce partial[NB_P][512] -> bag[512] ------------------------------
__global__ __launch_bounds__(256) void k_rbag(
    const float* __restrict__ partial, float* __restrict__ bag, int nb)
{
    int c = blockIdx.x * 16 + (threadIdx.x & 15);   // 32 blocks x 16 cols
    int r = threadIdx.x >> 4;                       // 16 row-groups
    float acc = 0.f;
    for (int b = r; b < nb; b += 16) acc += partial[(size_t)b * D + c];
    __shared__ float sm[256];
    sm[threadIdx.x] = acc;
    __syncthreads();
    if (threadIdx.x < 16) {
        float s = 0.f;
        #pragma unroll
        for (int q = 0; q < 16; ++q) s += sm[q * 16 + threadIdx.x];
        bag[blockIdx.x * 16 + threadIdx.x] = s;
    }
}

extern "C" void kernel_launch(void* const* d_in, const int* in_sizes, int n_in,
                              void* d_out, int out_size, void* d_ws, size_t ws_size,
                              hipStream_t stream) {
    const float* f  = (const float*)d_in[0];
    const float* aw = (const float*)d_in[1];
    const float* ab = (const float*)d_in[2];
    const int*   kp = (const int*)d_in[3];
    int n = in_sizes[0] / D;

    float* bag   = (float*)d_out;        // [512]
    float* w_out = (float*)d_out + D;    // [n]

    int nb1 = (n + R_BLK - 1) / R_BLK;   // pass-1 blocks (782)
    int nb2 = (n + 255) / 256;           // k_wu blocks (391)

    float* wsf     = (float*)d_ws;
    float* scores  = wsf;                        // n
    float* u       = wsf + n;                    // n
    float* pmax    = wsf + 2 * (size_t)n;        // nb1
    float* psum    = pmax + nb1;                 // nb1
    size_t poff    = ((2 * (size_t)n + 2 * (size_t)nb1) + 31) & ~(size_t)31;
    float* partial = wsf + poff;                 // NB_P * D

    int chunk = (n + NB_P - 1) / NB_P;

    k_scores<<<nb1, 512, 0, stream>>>(f, aw, ab, kp, scores, pmax, psum, n);
    k_wu    <<<nb2, 256, 0, stream>>>(scores, pmax, psum, nb1, kp, w_out, u, n);
    k_pbag  <<<NB_P, 128, 0, stream>>>(f, u, partial, n, chunk);
    k_rbag  <<<32, 256, 0, stream>>>(partial, bag, NB_P);
}

// Round 5
// 96.151 us; speedup vs baseline: 1.2174x; 1.2174x over previous
//
#include <hip/hip_runtime.h>
#include <math.h>

#define D 512
#define NB_P 1000   // partial-bag blocks (proven R1 config)

// ---------------- K1: dot[j] = features[j] . attn_w  (one wave per row) ----
// R1-proven version: 4 waves/block, 1 row per wave.
__global__ void k_dot(const float* __restrict__ f, const float* __restrict__ w,
                      float* __restrict__ dot, int n) {
    int wave = threadIdx.x >> 6;            // 4 waves / block
    int lane = threadIdx.x & 63;
    int row  = blockIdx.x * 4 + wave;
    if (row >= n) return;
    const float4* fr = (const float4*)(f + (size_t)row * D);
    const float4* wr = (const float4*)w;
    float4 a0 = fr[lane],      b0 = wr[lane];
    float4 a1 = fr[lane + 64], b1 = wr[lane + 64];
    float s = a0.x*b0.x + a0.y*b0.y + a0.z*b0.z + a0.w*b0.w
            + a1.x*b1.x + a1.y*b1.y + a1.z*b1.z + a1.w*b1.w;
    #pragma unroll
    for (int off = 32; off; off >>= 1) s += __shfl_down(s, off);
    if (lane == 0) dot[row] = s;
}

// ------- K2: scores + per-block softmax partials (m_b, s_b) ----------------
__global__ void k_scores(const float* __restrict__ dot, const float* __restrict__ bptr,
                         const int* __restrict__ kptr, float* __restrict__ scores,
                         float* __restrict__ pmax, float* __restrict__ psum, int n) {
    int i = blockIdx.x * 256 + threadIdx.x;
    int k = *kptr;
    float val = -INFINITY;
    if (i < n) {
        int lo = max(i - k, 0), hi = min(i + k, n - 1);
        float s = 0.f;
        for (int j = lo; j <= hi; ++j) s += dot[j];
        val = s / (float)(hi - lo + 1) + bptr[0];
        scores[i] = val;
    }
    __shared__ float sm[4];
    __shared__ float bmax;
    int lane = threadIdx.x & 63, wid = threadIdx.x >> 6;
    float m = val;
    #pragma unroll
    for (int off = 32; off; off >>= 1) m = fmaxf(m, __shfl_down(m, off));
    if (lane == 0) sm[wid] = m;
    __syncthreads();
    if (threadIdx.x == 0)
        bmax = fmaxf(fmaxf(sm[0], sm[1]), fmaxf(sm[2], sm[3]));
    __syncthreads();
    float mb = bmax;
    float e = (i < n) ? __expf(val - mb) : 0.f;
    #pragma unroll
    for (int off = 32; off; off >>= 1) e += __shfl_down(e, off);
    __syncthreads();               // sm reuse guard
    if (lane == 0) sm[wid] = e;
    __syncthreads();
    if (threadIdx.x == 0) {
        pmax[blockIdx.x] = mb;
        psum[blockIdx.x] = sm[0] + sm[1] + sm[2] + sm[3];
    }
}

// ---- K3: inline-combine partials, then w[j] and u[j] ------------------------
// u[j] = inv * sum_{i in win(j)} exp(scores[i]-gmax)/cnt(i)
__global__ void k_wu(const float* __restrict__ scores, const float* __restrict__ pmax,
                     const float* __restrict__ psum, int nb1,
                     const int* __restrict__ kptr, float* __restrict__ w_out,
                     float* __restrict__ u, int n) {
    __shared__ float sm[4];
    __shared__ float gshared[2];
    int lane = threadIdx.x & 63, wid = threadIdx.x >> 6;

    // global max (each block redundantly reduces nb1 entries — L2-hit, ~3 KB)
    float m = -INFINITY;
    for (int idx = threadIdx.x; idx < nb1; idx += 256) m = fmaxf(m, pmax[idx]);
    #pragma unroll
    for (int off = 32; off; off >>= 1) m = fmaxf(m, __shfl_down(m, off));
    if (lane == 0) sm[wid] = m;
    __syncthreads();
    if (threadIdx.x == 0)
        gshared[0] = fmaxf(fmaxf(sm[0], sm[1]), fmaxf(sm[2], sm[3]));
    __syncthreads();
    float gmax = gshared[0];

    // global sum
    float s = 0.f;
    for (int idx = threadIdx.x; idx < nb1; idx += 256)
        s += psum[idx] * __expf(pmax[idx] - gmax);
    #pragma unroll
    for (int off = 32; off; off >>= 1) s += __shfl_down(s, off);
    __syncthreads();               // sm reuse guard
    if (lane == 0) sm[wid] = s;
    __syncthreads();
    if (threadIdx.x == 0)
        gshared[1] = 1.f / (sm[0] + sm[1] + sm[2] + sm[3]);
    __syncthreads();
    float inv = gshared[1];

    int j = blockIdx.x * 256 + threadIdx.x;
    if (j >= n) return;
    int k = *kptr;
    float ej = __expf(scores[j] - gmax);
    w_out[j] = ej * inv;
    int lo = max(j - k, 0), hi = min(j + k, n - 1);
    float acc = 0.f;
    for (int i = lo; i <= hi; ++i) {
        int li = max(i - k, 0), hh = min(i + k, n - 1);
        float e = __expf(scores[i] - gmax);
        acc += e * __builtin_amdgcn_rcpf((float)(hh - li + 1));
    }
    u[j] = acc * inv;
}

// ---------------- K4: partial bag per block (R1-proven simple version) ------
__global__ void k_pbag(const float* __restrict__ f, const float* __restrict__ u,
                       float* __restrict__ partial, int n, int chunk) {
    int t = threadIdx.x;                         // 128 threads, float4 each = 512 cols
    int j0 = blockIdx.x * chunk;
    int j1 = min(j0 + chunk, n);
    float4 acc = make_float4(0.f, 0.f, 0.f, 0.f);
    for (int j = j0; j < j1; ++j) {
        float uj = u[j];
        float4 v = ((const float4*)(f + (size_t)j * D))[t];
        acc.x += uj * v.x; acc.y += uj * v.y;
        acc.z += uj * v.z; acc.w += uj * v.w;
    }
    ((float4*)(partial + (size_t)blockIdx.x * D))[t] = acc;
}

// ---------------- K5: reduce partial[NB_P][512] -> bag[512] -----------------
__global__ void k_rbag(const float* __restrict__ partial, float* __restrict__ bag, int nb) {
    int c = blockIdx.x * 16 + (threadIdx.x & 15);   // 32 blocks x 16 cols
    int r = threadIdx.x >> 4;                       // 16 row-groups
    float acc = 0.f;
    for (int b = r; b < nb; b += 16) acc += partial[(size_t)b * D + c];
    __shared__ float sm[256];
    sm[threadIdx.x] = acc;
    __syncthreads();
    if (threadIdx.x < 16) {
        float s = 0.f;
        #pragma unroll
        for (int q = 0; q < 16; ++q) s += sm[q * 16 + threadIdx.x];
        bag[blockIdx.x * 16 + threadIdx.x] = s;
    }
}

extern "C" void kernel_launch(void* const* d_in, const int* in_sizes, int n_in,
                              void* d_out, int out_size, void* d_ws, size_t ws_size,
                              hipStream_t stream) {
    const float* f  = (const float*)d_in[0];
    const float* aw = (const float*)d_in[1];
    const float* ab = (const float*)d_in[2];
    const int*   kp = (const int*)d_in[3];
    int n = in_sizes[0] / D;

    float* bag   = (float*)d_out;        // [512]
    float* w_out = (float*)d_out + D;    // [n]

    int nb2 = (n + 255) / 256;           // 391 blocks for scores / wu

    float* wsf     = (float*)d_ws;
    float* dot     = wsf;                        // n
    float* scores  = wsf + n;                    // n
    float* u       = wsf + 2 * (size_t)n;        // n
    float* pmax    = wsf + 3 * (size_t)n;        // nb2
    float* psum    = pmax + nb2;                 // nb2
    size_t poff    = ((3 * (size_t)n + 2 * (size_t)nb2) + 31) & ~(size_t)31;
    float* partial = wsf + poff;                 // NB_P * D

    int chunk = (n + NB_P - 1) / NB_P;

    k_dot   <<<(n + 3) / 4, 256, 0, stream>>>(f, aw, dot, n);
    k_scores<<<nb2, 256, 0, stream>>>(dot, ab, kp, scores, pmax, psum, n);
    k_wu    <<<nb2, 256, 0, stream>>>(scores, pmax, psum, nb2, kp, w_out, u, n);
    k_pbag  <<<NB_P, 128, 0, stream>>>(f, u, partial, n, chunk);
    k_rbag  <<<32, 256, 0, stream>>>(partial, bag, NB_P);
}